// Round 2
// baseline (414.252 us; speedup 1.0000x reference)
//
#include <hip/hip_runtime.h>
#include <stdint.h>

// Problem constants (SparseMPNN_30709016166923): B=2, N=40000, E=640000, H=4, F=32
#define BB     2
#define NNODE  40000
#define NEDGE  640000
#define NH     4
#define NF     32
#define NHF    128   // NH*NF
#define SEGN   (BB * NNODE)          // 80000 segments (b,node)
#define GEDGE  (BB * NEDGE)          // 1,280,000 global edges
#define SLOT   48                    // per-node bucket capacity (deg~Poisson(16))

// two-phase binning
#define W      512                   // nodes per coarse bucket (pow2)
#define NBK_B  79                    // ceil(40000/512) buckets per batch
#define NBK    (BB * NBK_B)          // 158 coarse buckets
#define CAP    9216                  // pairs per coarse bucket (mean 8192, +11 sigma)
#define BLK_E  2048                  // edges per binA block
#define NBLKA  (GEDGE / BLK_E)       // 625 (exact)

static constexpr float NEG_SLOPE = 0.2f;

// order-preserving float<->u32 encode for atomicMax-based segment max
__device__ __forceinline__ unsigned fenc(float f) {
    unsigned u = __float_as_uint(f);
    return (u & 0x80000000u) ? ~u : (u | 0x80000000u);
}
__device__ __forceinline__ float fdec(unsigned e) {
    unsigned u = (e & 0x80000000u) ? (e & 0x7FFFFFFFu) : ~e;
    return __uint_as_float(u);
}

// ---------- kernel 1: per-node attention logits + zero cursors/mpre ----------
__global__ void prep_k(const float* __restrict__ X,
                       const float* __restrict__ As,
                       const float* __restrict__ Aa,
                       float* __restrict__ S, float* __restrict__ A,
                       unsigned* __restrict__ cursor,
                       unsigned* __restrict__ mpre) {
    int idx = blockIdx.x * blockDim.x + threadIdx.x;   // (b,n,h)
    if (idx < NBK) cursor[idx] = 0u;                   // fused cursor zero-init
    if (idx >= SEGN * NH) return;
    mpre[idx] = 0u;                                    // enc-space -inf (< enc of any real float)
    int h = idx & (NH - 1);
    const float4* xv = (const float4*)(X + (size_t)idx * NF);
    const float4* sv = (const float4*)(As + h * NF);
    const float4* av = (const float4*)(Aa + h * NF);
    float s = 0.f, a = 0.f;
#pragma unroll
    for (int i = 0; i < 8; ++i) {
        float4 x = xv[i];
        float4 ws = sv[i];
        float4 wa = av[i];
        s += x.x * ws.x + x.y * ws.y + x.z * ws.z + x.w * ws.w;
        a += x.x * wa.x + x.y * wa.y + x.z * wa.z + x.w * wa.w;
    }
    S[idx] = s;
    A[idx] = a;
}

// ---------- kernel 2 (bin phase A): coarse partition + fused segment-max ----------
// R10: while tg/sc are in registers, also compute v = lrelu(S[tg]+A[sc]) for all
// 4 heads (S/A are 2.5MB total -> L2-resident) and atomicMax into mpre. This
// removes the online-softmax (running max + rescale) from gather_k entirely.
// atomicMax is order-invariant -> deterministic. v computed with identical op
// order (add, then lrelu) as gather_k -> exp(v - m1) == 1.0 exactly at the max,
// so the m2 normalization pass stays eliminated (1.0f + 1e-9f == 1.0f).
__global__ __launch_bounds__(256) void binA_k(const int* __restrict__ tg,
                                              const int* __restrict__ sc,
                                              const float* __restrict__ S,
                                              const float* __restrict__ A,
                                              unsigned* __restrict__ cursor,
                                              unsigned* __restrict__ pairs,
                                              unsigned* __restrict__ mpre) {
    __shared__ unsigned hist[NBK];
    __shared__ unsigned lofs[NBK];
    __shared__ unsigned gofs[NBK];
    __shared__ unsigned wsum[4];
    __shared__ unsigned staged[BLK_E];
    __shared__ unsigned char sbk[BLK_E];
    int t = threadIdx.x;
    int base = blockIdx.x * BLK_E;
    for (int i = t; i < NBK; i += 256) hist[i] = 0u;
    __syncthreads();

    unsigned pr[8];
    unsigned short pbk[8], plp[8];
#pragma unroll
    for (int k = 0; k < 8; ++k) {
        int e = base + k * 256 + t;                    // exact: 625*2048 == GEDGE
        int tgv = tg[e], scv = sc[e];
        int b = (e >= NEDGE) ? 1 : 0;
        unsigned bk = (unsigned)(b * NBK_B + (tgv >> 9));
        pr[k]  = ((unsigned)(tgv & (W - 1)) << 16) | (unsigned)scv;  // src<40000 fits u16
        pbk[k] = (unsigned short)bk;
        plp[k] = (unsigned short)atomicAdd(&hist[bk], 1u);
        // fused per-edge logit + segment max (4 heads)
        int tgg = b * NNODE + tgv;
        int sgg = b * NNODE + scv;
        float4 sv4 = *(const float4*)(S + (size_t)tgg * NH);
        float4 av4 = *(const float4*)(A + (size_t)sgg * NH);
        float v0 = sv4.x + av4.x; v0 = v0 > 0.f ? v0 : NEG_SLOPE * v0;
        float v1 = sv4.y + av4.y; v1 = v1 > 0.f ? v1 : NEG_SLOPE * v1;
        float v2 = sv4.z + av4.z; v2 = v2 > 0.f ? v2 : NEG_SLOPE * v2;
        float v3 = sv4.w + av4.w; v3 = v3 > 0.f ? v3 : NEG_SLOPE * v3;
        unsigned* mp = mpre + (size_t)tgg * NH;
        atomicMax(mp + 0, fenc(v0));
        atomicMax(mp + 1, fenc(v1));
        atomicMax(mp + 2, fenc(v2));
        atomicMax(mp + 3, fenc(v3));
    }
    __syncthreads();
    // parallel exclusive scan of hist[0..NBK) -> lofs
    {
        int lane = t & 63, w = t >> 6;
        unsigned v = (t < NBK) ? hist[t] : 0u;
        unsigned inc = v;
#pragma unroll
        for (int d = 1; d < 64; d <<= 1) {
            unsigned u = __shfl_up(inc, d);
            if (lane >= d) inc += u;
        }
        if (lane == 63) wsum[w] = inc;
        __syncthreads();
        unsigned woff = 0;
#pragma unroll
        for (int i = 0; i < 3; ++i) { if (i < w) woff += wsum[i]; }
        if (t < NBK) {
            lofs[t] = woff + inc - v;                  // exclusive prefix
            if (v > 0u)
                gofs[t] = atomicAdd(&cursor[t], v);    // one reserve per bucket
        }
    }
    __syncthreads();
#pragma unroll
    for (int k = 0; k < 8; ++k) {
        unsigned j = lofs[pbk[k]] + plp[k];
        staged[j] = pr[k];
        sbk[j] = (unsigned char)pbk[k];
    }
    __syncthreads();
    for (int j = t; j < BLK_E; j += 256) {
        unsigned bk = sbk[j];
        unsigned dst = gofs[bk] + ((unsigned)j - lofs[bk]);
        if (dst < CAP)                                  // 11-sigma guard
            pairs[(size_t)bk * CAP + dst] = staged[j];
    }
}

// ---------- kernel 3 (bin phase B): fine-bin one coarse bucket in LDS ----------
__global__ __launch_bounds__(1024) void binB_k(const unsigned* __restrict__ cursor,
                                               const unsigned* __restrict__ pairs,
                                               unsigned short* __restrict__ srt,
                                               unsigned* __restrict__ deg) {
    __shared__ unsigned short loc[W * SLOT];            // 49,152 B
    __shared__ unsigned dloc[W];
    int t = threadIdx.x;
    int gbk = blockIdx.x;                               // 0..157
    int b = gbk / NBK_B;
    int bkloc = gbk - b * NBK_B;
    int node0 = b * NNODE + bkloc * W;
    int wEff = min(W, NNODE - bkloc * W);               // 512 (or 64 for last bucket)
    for (int i = t; i < W; i += 1024) dloc[i] = 0u;
    __syncthreads();
    int nE = (int)min(cursor[gbk], (unsigned)CAP);
    const unsigned* pb = pairs + (size_t)gbk * CAP;
    for (int j = t; j < nE; j += 1024) {
        unsigned p = pb[j];
        unsigned tl = p >> 16;                          // node local to bucket
        unsigned pos = atomicAdd(&dloc[tl], 1u);
        if (pos < SLOT)
            loc[tl * SLOT + pos] = (unsigned short)(p & 0xFFFFu);
    }
    __syncthreads();
    unsigned* srt32 = (unsigned*)(srt + (size_t)node0 * SLOT);  // 96B/node, 4B-aligned
    const unsigned* loc32 = (const unsigned*)loc;
    int n32 = wEff * SLOT / 2;
    for (int i = t; i < n32; i += 1024) srt32[i] = loc32[i];    // full-line streams
    for (int i = t; i < wEff; i += 1024) deg[node0 + i] = dloc[i];
}

// ---------- kernel 4: gather — flat pipeline, precomputed max, zero LDS ----------
// R10 restructure: with mpre (segment max) precomputed in binA, the online
// softmax (per-chunk 4-shfl max chain + acc rescale) is gone, and with it the
// chunk-to-chunk serial dependency. Stage all <=48 edges as 3 independent
// 16-edge groups (lane t: edge t>>2, head t&3 -> w = exp(v - m1), src), then
// a fully-unrolled 24-pair accumulate: every float4 X load is independent ->
// up to 24 outstanding loads/lane (vs 8/chunk serialized before), 2 fewer
// dependent memory stages. Lane t owns f-quad q=t&31; halves h32 accumulate
// even/odd edges; merge via shfl_xor(32). 4 nodes (4 waves) per block.
__global__ __launch_bounds__(256) void gather_k(
        const float* __restrict__ X, const float* __restrict__ S,
        const float* __restrict__ A, const unsigned* __restrict__ deg,
        const unsigned short* __restrict__ srt,
        const unsigned* __restrict__ mpre, float* __restrict__ OUT) {
    int node = blockIdx.x * 4 + (threadIdx.x >> 6);
    int t = threadIdx.x & 63;                   // lane 0..63
    int hs = t & 3;                             // staging head
    int es = t >> 2;                            // staging edge slot 0..15 within group
    int h32 = t >> 5;                           // which edge of the pair
    int q = t & 31;                             // f-quad index 0..31
    int haq = q >> 3;                           // accumulation head for quad
    int dg = min((int)deg[node], SLOT);
    int bbase = (node >= NNODE) ? NNODE : 0;
    size_t beg = (size_t)node * SLOT;

    float sh = S[node * NH + hs];
    float mh = fdec(mpre[node * NH + hs]);      // exact segment max (m1)

    float w[3];
    int   sb[3];
#pragma unroll
    for (int c = 0; c < 3; ++c) {
        int e = 16 * c + es;
        int s0 = bbase;
        float wv = 0.f;
        if (e < dg) {
            s0 = bbase + (int)srt[beg + e];
            float v = sh + A[s0 * NH + hs];
            v = v > 0.f ? v : NEG_SLOPE * v;
            wv = __expf(v - mh);                // in (0,1], max lane == 1.0 exactly
        }
        sb[c] = s0;
        w[c]  = wv;
    }

    float4 acc = make_float4(0.f, 0.f, 0.f, 0.f);
#pragma unroll
    for (int i = 0; i < 24; ++i) {              // i>>3 = group, compile-time after unroll
        if (2 * i < dg) {                       // wave-uniform guard
            int e2 = 2 * i + h32;               // may equal dg (odd dg): w==0, sb==bbase -> safe
            float we  = __shfl(w[i >> 3],  4 * (e2 & 15) + haq);
            int   sbe = __shfl(sb[i >> 3], 4 * (e2 & 15));
            const float4 x = *(const float4*)(X + (size_t)sbe * NHF + 4 * q);
            acc.x += x.x * we;
            acc.y += x.y * we;
            acc.z += x.z * we;
            acc.w += x.w * we;
        }
    }
    // merge even/odd-edge halves (identical scaling: both use m1)
    acc.x += __shfl_xor(acc.x, 32);
    acc.y += __shfl_xor(acc.y, 32);
    acc.z += __shfl_xor(acc.z, 32);
    acc.w += __shfl_xor(acc.w, 32);
    if (t < 32) {
        float4* o = (float4*)(OUT + (size_t)node * NHF + 4 * q);
        *o = acc;                               // every node written: no OUT init
    }
}

extern "C" void kernel_launch(void* const* d_in, const int* in_sizes, int n_in,
                              void* d_out, int out_size, void* d_ws, size_t ws_size,
                              hipStream_t stream) {
    const float* X  = (const float*)d_in[0];
    const float* As = (const float*)d_in[1];
    const float* Aa = (const float*)d_in[2];
    const int* tg = (const int*)d_in[4];
    const int* sc = (const int*)d_in[5];
    float* OUT = (float*)d_out;

    // Workspace layout, total 17,665,152 B (proven safe: R7 ran with ws_size
    // >= 18,240,000; R1 proved ~24.3MB overflows and corrupts harness state):
    //   S      @ 0          : 1,280,000  (SEGN*NH fp32)
    //   A      @ 1,280,000  : 1,280,000
    //   deg    @ 2,560,000  :   320,000  (SEGN u32)
    //   cursor @ 2,880,000  :       640  (NBK u32, padded)
    //   pairs  @ 2,880,640  : 5,824,512  (NBK*CAP u32)
    //   srt    @ 8,705,152  : 7,680,000  (SEGN*SLOT u16)
    //   mpre   @ 16,385,152 : 1,280,000  (SEGN*NH u32, enc-space segment max)
    char* ws = (char*)d_ws;
    float*          S      = (float*)ws;
    float*          A      = (float*)(ws + 1280000);
    unsigned*       deg    = (unsigned*)(ws + 2560000);
    unsigned*       cursor = (unsigned*)(ws + 2880000);
    unsigned*       pairs  = (unsigned*)(ws + 2880640);
    unsigned short* srt    = (unsigned short*)(ws + 8705152);
    unsigned*       mpre   = (unsigned*)(ws + 16385152);

    const int nlog = SEGN * NH;                  // 320,000
    prep_k<<<(nlog + 255) / 256, 256, 0, stream>>>(X, As, Aa, S, A, cursor, mpre);
    binA_k<<<NBLKA, 256, 0, stream>>>(tg, sc, S, A, cursor, pairs, mpre);
    binB_k<<<NBK, 1024, 0, stream>>>(cursor, pairs, srt, deg);
    gather_k<<<SEGN / 4, 256, 0, stream>>>(X, S, A, deg, srt, mpre, OUT);
}

// Round 3
// 219.210 us; speedup vs baseline: 1.8897x; 1.8897x over previous
//
#include <hip/hip_runtime.h>
#include <stdint.h>

// Problem constants (SparseMPNN_30709016166923): B=2, N=40000, E=640000, H=4, F=32
#define BB     2
#define NNODE  40000
#define NEDGE  640000
#define NH     4
#define NF     32
#define NHF    128   // NH*NF
#define SEGN   (BB * NNODE)          // 80000 segments (b,node)
#define GEDGE  (BB * NEDGE)          // 1,280,000 global edges
#define SLOT   48                    // per-node bucket capacity (deg~Poisson(16))

// two-phase binning
#define W      512                   // nodes per coarse bucket (pow2)
#define NBK_B  79                    // ceil(40000/512) buckets per batch
#define NBK    (BB * NBK_B)          // 158 coarse buckets
#define CAP    9216                  // pairs per coarse bucket (mean 8192, +11 sigma)
#define BLK_E  2048                  // edges per binA block
#define NBLKA  (GEDGE / BLK_E)       // 625 (exact)

static constexpr float NEG_SLOPE = 0.2f;
static constexpr float NEG_BIG   = -3.4e38f;

// ---------- kernel 1: per-node attention logits + zero bucket cursors ----------
__global__ void prep_k(const float* __restrict__ X,
                       const float* __restrict__ As,
                       const float* __restrict__ Aa,
                       float* __restrict__ S, float* __restrict__ A,
                       unsigned* __restrict__ cursor) {
    int idx = blockIdx.x * blockDim.x + threadIdx.x;   // (b,n,h)
    if (idx < NBK) cursor[idx] = 0u;                   // fused cursor zero-init
    if (idx >= SEGN * NH) return;
    int h = idx & (NH - 1);
    const float4* xv = (const float4*)(X + (size_t)idx * NF);
    const float4* sv = (const float4*)(As + h * NF);
    const float4* av = (const float4*)(Aa + h * NF);
    float s = 0.f, a = 0.f;
#pragma unroll
    for (int i = 0; i < 8; ++i) {
        float4 x = xv[i];
        float4 ws = sv[i];
        float4 wa = av[i];
        s += x.x * ws.x + x.y * ws.y + x.z * ws.z + x.w * ws.w;
        a += x.x * wa.x + x.y * wa.y + x.z * wa.z + x.w * wa.w;
    }
    S[idx] = s;
    A[idx] = a;
}

// ---------- kernel 2 (bin phase A): coarse partition, LDS-sorted coalesced writes ----------
// R11: reverted to R9 form. R10's fused global atomicMax (5.12M scattered
// atomics) made this kernel 213us with WRITE_SIZE=166MB, VALUBusy=1% — the
// segment max is now computed in-register inside gather_k instead.
__global__ __launch_bounds__(256) void binA_k(const int* __restrict__ tg,
                                              const int* __restrict__ sc,
                                              unsigned* __restrict__ cursor,
                                              unsigned* __restrict__ pairs) {
    __shared__ unsigned hist[NBK];
    __shared__ unsigned lofs[NBK];
    __shared__ unsigned gofs[NBK];
    __shared__ unsigned wsum[4];
    __shared__ unsigned staged[BLK_E];
    __shared__ unsigned char sbk[BLK_E];
    int t = threadIdx.x;
    int base = blockIdx.x * BLK_E;
    for (int i = t; i < NBK; i += 256) hist[i] = 0u;
    __syncthreads();

    unsigned pr[8];
    unsigned short pbk[8], plp[8];
#pragma unroll
    for (int k = 0; k < 8; ++k) {
        int e = base + k * 256 + t;                    // exact: 625*2048 == GEDGE
        int tgv = tg[e], scv = sc[e];
        int b = (e >= NEDGE) ? 1 : 0;
        unsigned bk = (unsigned)(b * NBK_B + (tgv >> 9));
        pr[k]  = ((unsigned)(tgv & (W - 1)) << 16) | (unsigned)scv;  // src<40000 fits u16
        pbk[k] = (unsigned short)bk;
        plp[k] = (unsigned short)atomicAdd(&hist[bk], 1u);
    }
    __syncthreads();
    // parallel exclusive scan of hist[0..NBK) -> lofs
    {
        int lane = t & 63, w = t >> 6;
        unsigned v = (t < NBK) ? hist[t] : 0u;
        unsigned inc = v;
#pragma unroll
        for (int d = 1; d < 64; d <<= 1) {
            unsigned u = __shfl_up(inc, d);
            if (lane >= d) inc += u;
        }
        if (lane == 63) wsum[w] = inc;
        __syncthreads();
        unsigned woff = 0;
#pragma unroll
        for (int i = 0; i < 3; ++i) { if (i < w) woff += wsum[i]; }
        if (t < NBK) {
            lofs[t] = woff + inc - v;                  // exclusive prefix
            if (v > 0u)
                gofs[t] = atomicAdd(&cursor[t], v);    // one reserve per bucket
        }
    }
    __syncthreads();
#pragma unroll
    for (int k = 0; k < 8; ++k) {
        unsigned j = lofs[pbk[k]] + plp[k];
        staged[j] = pr[k];
        sbk[j] = (unsigned char)pbk[k];
    }
    __syncthreads();
    for (int j = t; j < BLK_E; j += 256) {
        unsigned bk = sbk[j];
        unsigned dst = gofs[bk] + ((unsigned)j - lofs[bk]);
        if (dst < CAP)                                  // 11-sigma guard
            pairs[(size_t)bk * CAP + dst] = staged[j];
    }
}

// ---------- kernel 3 (bin phase B): fine-bin one coarse bucket in LDS ----------
__global__ __launch_bounds__(1024) void binB_k(const unsigned* __restrict__ cursor,
                                               const unsigned* __restrict__ pairs,
                                               unsigned short* __restrict__ srt,
                                               unsigned* __restrict__ deg) {
    __shared__ unsigned short loc[W * SLOT];            // 49,152 B
    __shared__ unsigned dloc[W];
    int t = threadIdx.x;
    int gbk = blockIdx.x;                               // 0..157
    int b = gbk / NBK_B;
    int bkloc = gbk - b * NBK_B;
    int node0 = b * NNODE + bkloc * W;
    int wEff = min(W, NNODE - bkloc * W);               // 512 (or 64 for last bucket)
    for (int i = t; i < W; i += 1024) dloc[i] = 0u;
    __syncthreads();
    int nE = (int)min(cursor[gbk], (unsigned)CAP);
    const unsigned* pb = pairs + (size_t)gbk * CAP;
    for (int j = t; j < nE; j += 1024) {
        unsigned p = pb[j];
        unsigned tl = p >> 16;                          // node local to bucket
        unsigned pos = atomicAdd(&dloc[tl], 1u);
        if (pos < SLOT)
            loc[tl * SLOT + pos] = (unsigned short)(p & 0xFFFFu);
    }
    __syncthreads();
    unsigned* srt32 = (unsigned*)(srt + (size_t)node0 * SLOT);  // 96B/node, 4B-aligned
    const unsigned* loc32 = (const unsigned*)loc;
    int n32 = wEff * SLOT / 2;
    for (int i = t; i < n32; i += 1024) srt32[i] = loc32[i];    // full-line streams
    for (int i = t; i < wEff; i += 1024) deg[node0 + i] = dloc[i];
}

// ---------- kernel 4: gather — flat pipeline, in-register segment max ----------
// R11: segment max m1 computed IN-REGISTER from the staged logits: the wave
// holds all <=48 edge logits (lane t = edge t>>2, head t&3, 3 groups), so
// m1 = 3 fmax + shfl_xor(4/8/16/32) within head class. No atomics, no online
// softmax, no chunk-serial coupling. X-load addresses depend only on srt (not
// on w or the max), so the kernel's dependent memory depth is srt -> X; all 24
// float4 X loads per lane are independent. exp(v-m1)==1.0 exactly at the max
// lane -> m2 normalization pass stays eliminated (1.0f + 1e-9f == 1.0f,
// verified R3-R10, absmax 0.03125).
// Lane t owns f-quad q=t&31; halves h32=t>>5 accumulate even/odd edges; merge
// via shfl_xor(32). 4 nodes (4 waves) per block.
__global__ __launch_bounds__(256) void gather_k(
        const float* __restrict__ X, const float* __restrict__ S,
        const float* __restrict__ A, const unsigned* __restrict__ deg,
        const unsigned short* __restrict__ srt, float* __restrict__ OUT) {
    int node = blockIdx.x * 4 + (threadIdx.x >> 6);
    int t = threadIdx.x & 63;                   // lane 0..63
    int hs = t & 3;                             // staging head
    int es = t >> 2;                            // staging edge slot 0..15 within group
    int h32 = t >> 5;                           // which edge of the pair
    int q = t & 31;                             // f-quad index 0..31
    int haq = q >> 3;                           // accumulation head for quad
    int dg = min((int)deg[node], SLOT);
    int bbase = (node >= NNODE) ? NNODE : 0;
    size_t beg = (size_t)node * SLOT;

    float sh = S[node * NH + hs];

    // stage: logits for all <=48 edges, 3 independent groups
    float v[3];
    int   sb[3];
#pragma unroll
    for (int c = 0; c < 3; ++c) {
        int e = 16 * c + es;
        int s0 = bbase;
        float vv = NEG_BIG;
        if (e < dg) {
            s0 = bbase + (int)srt[beg + e];
            vv = sh + A[s0 * NH + hs];
            vv = vv > 0.f ? vv : NEG_SLOPE * vv;
        }
        sb[c] = s0;
        v[c]  = vv;
    }
    // in-register segment max per head class (lanes ≡ hs mod 4)
    float m = fmaxf(fmaxf(v[0], v[1]), v[2]);
    m = fmaxf(m, __shfl_xor(m, 4));
    m = fmaxf(m, __shfl_xor(m, 8));
    m = fmaxf(m, __shfl_xor(m, 16));
    m = fmaxf(m, __shfl_xor(m, 32));
    float w[3];
#pragma unroll
    for (int c = 0; c < 3; ++c)
        w[c] = (16 * c + es < dg) ? __expf(v[c] - m) : 0.f;  // in (0,1], max lane == 1.0

    float4 acc = make_float4(0.f, 0.f, 0.f, 0.f);
#pragma unroll
    for (int i = 0; i < 24; ++i) {              // i>>3 = group, compile-time after unroll
        if (2 * i < dg) {                       // wave-uniform guard
            int e2 = 2 * i + h32;               // may equal dg (odd dg): w==0, sb==bbase -> safe
            float we  = __shfl(w[i >> 3],  4 * (e2 & 15) + haq);
            int   sbe = __shfl(sb[i >> 3], 4 * (e2 & 15));
            const float4 x = *(const float4*)(X + (size_t)sbe * NHF + 4 * q);
            acc.x += x.x * we;
            acc.y += x.y * we;
            acc.z += x.z * we;
            acc.w += x.w * we;
        }
    }
    // merge even/odd-edge halves (identical scaling: both use m1)
    acc.x += __shfl_xor(acc.x, 32);
    acc.y += __shfl_xor(acc.y, 32);
    acc.z += __shfl_xor(acc.z, 32);
    acc.w += __shfl_xor(acc.w, 32);
    if (t < 32) {
        float4* o = (float4*)(OUT + (size_t)node * NHF + 4 * q);
        *o = acc;                               // every node written: no OUT init
    }
}

extern "C" void kernel_launch(void* const* d_in, const int* in_sizes, int n_in,
                              void* d_out, int out_size, void* d_ws, size_t ws_size,
                              hipStream_t stream) {
    const float* X  = (const float*)d_in[0];
    const float* As = (const float*)d_in[1];
    const float* Aa = (const float*)d_in[2];
    const int* tg = (const int*)d_in[4];
    const int* sc = (const int*)d_in[5];
    float* OUT = (float*)d_out;

    // Workspace layout, total 16,385,152 B (proven safe: R7 ran with ws_size
    // >= 18,240,000; R1 proved ~24.3MB overflows and corrupts harness state):
    //   S      @ 0          : 1,280,000  (SEGN*NH fp32)
    //   A      @ 1,280,000  : 1,280,000
    //   deg    @ 2,560,000  :   320,000  (SEGN u32)
    //   cursor @ 2,880,000  :       640  (NBK u32, padded)
    //   pairs  @ 2,880,640  : 5,824,512  (NBK*CAP u32)
    //   srt    @ 8,705,152  : 7,680,000  (SEGN*SLOT u16)
    char* ws = (char*)d_ws;
    float*          S      = (float*)ws;
    float*          A      = (float*)(ws + 1280000);
    unsigned*       deg    = (unsigned*)(ws + 2560000);
    unsigned*       cursor = (unsigned*)(ws + 2880000);
    unsigned*       pairs  = (unsigned*)(ws + 2880640);
    unsigned short* srt    = (unsigned short*)(ws + 8705152);

    const int nlog = SEGN * NH;                  // 320,000
    prep_k<<<(nlog + 255) / 256, 256, 0, stream>>>(X, As, Aa, S, A, cursor);
    binA_k<<<NBLKA, 256, 0, stream>>>(tg, sc, cursor, pairs);
    binB_k<<<NBK, 1024, 0, stream>>>(cursor, pairs, srt, deg);
    gather_k<<<SEGN / 4, 256, 0, stream>>>(X, S, A, deg, srt, OUT);
}